// Round 1
// baseline (1108.328 us; speedup 1.0000x reference)
//
#include <hip/hip_runtime.h>
#include <cstdint>
#include <cstddef>

#define NN 100000
#define NE 1600000
#define NTOT (NE + NN)      // 1700000 edges incl self-loops
#define HF 128              // hidden features
#define OF 64               // output features

// ---------------- graph preprocessing ----------------

__global__ __launch_bounds__(256) void k_init(int* flag, int* deg) {
    int i = blockIdx.x * 256 + threadIdx.x;
    if (i == 0) *flag = 0;
    if (i < NN) deg[i] = 1;   // self-loop
}

// OR-reduce the odd 32-bit words of the first 2E words of edge_index.
// int64 data (little-endian, values < N) -> all high halves zero -> flag stays 0.
// int32 data -> odd words are real indices, almost surely nonzero -> flag = 1.
__global__ __launch_bounds__(256) void k_detect(const int* ei, int* flag) {
    int t = blockIdx.x * blockDim.x + threadIdx.x;
    int v = 0;
    for (int i = t; i < NE; i += gridDim.x * blockDim.x) v |= ei[2 * i + 1];
    unsigned long long b = __ballot(v != 0);
    if ((threadIdx.x & 63) == 0 && b) atomicOr(flag, 1);
}

__device__ __forceinline__ int edge_src(const int* ei, int e, bool is64) {
    return is64 ? ei[2 * e] : ei[e];
}
__device__ __forceinline__ int edge_dst(const int* ei, int e, bool is64) {
    return is64 ? ei[2 * (NE + e)] : ei[NE + e];
}

__global__ __launch_bounds__(256) void k_hist(const int* ei, const int* flag, int* deg) {
    int e = blockIdx.x * 256 + threadIdx.x;
    if (e >= NE) return;
    bool is64 = (*flag) == 0;
    atomicAdd(&deg[edge_dst(ei, e, is64)], 1);
}

__global__ __launch_bounds__(256) void k_dinv(const int* deg, float* dinv) {
    int i = blockIdx.x * 256 + threadIdx.x;
    if (i < NN) dinv[i] = rsqrtf((float)deg[i]);   // deg >= 1 always (self-loop)
}

// exclusive scan of deg[N] -> rowptr, 1024 elems per block
__global__ __launch_bounds__(256) void k_scanA(const int* deg, int* rowptr, int* bsum) {
    __shared__ int sh[256];
    int tid = threadIdx.x;
    int base = blockIdx.x * 1024 + tid * 4;
    int v0 = 0, v1 = 0, v2 = 0, v3 = 0;
    if (base + 0 < NN) v0 = deg[base + 0];
    if (base + 1 < NN) v1 = deg[base + 1];
    if (base + 2 < NN) v2 = deg[base + 2];
    if (base + 3 < NN) v3 = deg[base + 3];
    int s = v0 + v1 + v2 + v3;
    sh[tid] = s;
    __syncthreads();
    for (int off = 1; off < 256; off <<= 1) {
        int t = (tid >= off) ? sh[tid - off] : 0;
        __syncthreads();
        sh[tid] += t;
        __syncthreads();
    }
    int run = sh[tid] - s;   // exclusive start for this thread's 4 elems
    if (base + 0 < NN) rowptr[base + 0] = run; run += v0;
    if (base + 1 < NN) rowptr[base + 1] = run; run += v1;
    if (base + 2 < NN) rowptr[base + 2] = run; run += v2;
    if (base + 3 < NN) rowptr[base + 3] = run;
    if (tid == 255) bsum[blockIdx.x] = sh[255];
}

__global__ __launch_bounds__(128) void k_scanB(const int* bsum, int* boff, int* rowptr) {
    __shared__ int sh[128];
    int tid = threadIdx.x;
    int v = (tid < 98) ? bsum[tid] : 0;
    sh[tid] = v;
    __syncthreads();
    for (int off = 1; off < 128; off <<= 1) {
        int t = (tid >= off) ? sh[tid - off] : 0;
        __syncthreads();
        sh[tid] += t;
        __syncthreads();
    }
    if (tid < 98) boff[tid] = sh[tid] - v;
    if (tid == 0) rowptr[NN] = NTOT;   // total degree is exactly E+N
}

__global__ __launch_bounds__(256) void k_scanC(int* rowptr, const int* boff, int* cursor) {
    int i = blockIdx.x * 256 + threadIdx.x;
    if (i < NN) {
        int r = rowptr[i] + boff[i >> 10];
        rowptr[i] = r;
        cursor[i] = r;
    }
}

__global__ __launch_bounds__(256) void k_scatter(const int* ei, const int* flag,
                                                 int* cursor, int* csr) {
    int e = blockIdx.x * 256 + threadIdx.x;
    if (e >= NTOT) return;
    bool is64 = (*flag) == 0;
    int s, d;
    if (e < NE) { s = edge_src(ei, e, is64); d = edge_dst(ei, e, is64); }
    else        { s = e - NE; d = s; }
    int pos = atomicAdd(&cursor[d], 1);
    csr[pos] = s;
}

// ---------------- dense compute ----------------

// Out[r][:] = dinv[r] * (A[r][:] @ W)   A:[N][128] W:[128][128]
// block: 256 thr, 64-row tile; thread (tx=tid&31 -> 4 cols, ty=tid>>5 -> 8 rows)
__global__ __launch_bounds__(256) void k_mm128(const float* __restrict__ A,
                                               const float* __restrict__ W,
                                               const float* __restrict__ dinv,
                                               float* __restrict__ Out) {
    __shared__ float At[64][33];     // +1 pad: conflict-free reads
    __shared__ float Wt[32][128];
    int tid = threadIdx.x;
    int tx = tid & 31, ty = tid >> 5;
    int row0 = blockIdx.x * 64;
    float acc[8][4];
#pragma unroll
    for (int j = 0; j < 8; ++j)
#pragma unroll
        for (int c = 0; c < 4; ++c) acc[j][c] = 0.f;

    for (int kb = 0; kb < 128; kb += 32) {
#pragma unroll
        for (int i = 0; i < 4; ++i) {                 // W chunk 32x128
            int kr = ty + i * 8;
            float4 wv = *(const float4*)&W[(size_t)(kb + kr) * 128 + tx * 4];
            *(float4*)&Wt[kr][tx * 4] = wv;
        }
#pragma unroll
        for (int i = 0; i < 8; ++i) {                 // A chunk 64x32
            int r = ty + i * 8;
            int gr = row0 + r;
            At[r][tx] = (gr < NN) ? A[(size_t)gr * 128 + kb + tx] : 0.f;
        }
        __syncthreads();
#pragma unroll 4
        for (int k = 0; k < 32; ++k) {
            float4 wv = *(const float4*)&Wt[k][tx * 4];
#pragma unroll
            for (int j = 0; j < 8; ++j) {
                float a = At[ty * 8 + j][k];
                acc[j][0] += a * wv.x;
                acc[j][1] += a * wv.y;
                acc[j][2] += a * wv.z;
                acc[j][3] += a * wv.w;
            }
        }
        __syncthreads();
    }
#pragma unroll
    for (int j = 0; j < 8; ++j) {
        int r = row0 + ty * 8 + j;
        if (r < NN) {
            float sc = dinv[r];
            float4 o = make_float4(acc[j][0] * sc, acc[j][1] * sc,
                                   acc[j][2] * sc, acc[j][3] * sc);
            *(float4*)&Out[(size_t)r * 128 + tx * 4] = o;
        }
    }
}

// h_out[d][:] = relu(dinv[d] * sum_{s in N(d)} m[s][:] + b)   one wave per node
__global__ __launch_bounds__(256) void k_agg(const int* __restrict__ rowptr,
                                             const int* __restrict__ csr,
                                             const float* __restrict__ m,
                                             const float* __restrict__ dinv,
                                             const float* __restrict__ bias,
                                             float* __restrict__ out) {
    int w = threadIdx.x >> 6, lane = threadIdx.x & 63;
    int node = blockIdx.x * 4 + w;
    if (node >= NN) return;
    int beg = rowptr[node], end = rowptr[node + 1];
    const float2* mp = (const float2*)m;
    float ax = 0.f, ay = 0.f;
    int i = beg;
    for (; i + 4 <= end; i += 4) {
        int s0 = csr[i], s1 = csr[i + 1], s2 = csr[i + 2], s3 = csr[i + 3];
        float2 v0 = mp[(size_t)s0 * 64 + lane];
        float2 v1 = mp[(size_t)s1 * 64 + lane];
        float2 v2 = mp[(size_t)s2 * 64 + lane];
        float2 v3 = mp[(size_t)s3 * 64 + lane];
        ax += (v0.x + v1.x) + (v2.x + v3.x);
        ay += (v0.y + v1.y) + (v2.y + v3.y);
    }
    for (; i < end; ++i) {
        int s = csr[i];
        float2 v = mp[(size_t)s * 64 + lane];
        ax += v.x; ay += v.y;
    }
    float sc = dinv[node];
    float2 bb = ((const float2*)bias)[lane];
    float rx = fmaxf(ax * sc + bb.x, 0.f);
    float ry = fmaxf(ay * sc + bb.y, 0.f);
    ((float2*)out)[(size_t)node * 64 + lane] = make_float2(rx, ry);
}

// logits[r][:] (+)= H[r][:] @ Wl (128x64);  first layer initializes with lin_b
__global__ __launch_bounds__(256) void k_jk(const float* __restrict__ Hl,
                                            const float* __restrict__ Wl,
                                            const float* __restrict__ linb,
                                            float* __restrict__ logits, int first) {
    __shared__ float At[64][33];
    __shared__ float Wt[32][64];
    int tid = threadIdx.x;
    int tx = tid & 15, ty = tid >> 4;     // tx: 4 cols, ty: 4 rows
    int row0 = blockIdx.x * 64;
    float acc[4][4];
#pragma unroll
    for (int j = 0; j < 4; ++j)
#pragma unroll
        for (int c = 0; c < 4; ++c) acc[j][c] = 0.f;

    for (int kb = 0; kb < 128; kb += 32) {
#pragma unroll
        for (int i = 0; i < 2; ++i) {                 // W chunk 32x64
            int kr = (tid >> 4) + i * 16;
            float4 wv = *(const float4*)&Wl[(size_t)(kb + kr) * 64 + (tid & 15) * 4];
            *(float4*)&Wt[kr][(tid & 15) * 4] = wv;
        }
#pragma unroll
        for (int i = 0; i < 8; ++i) {                 // A chunk 64x32
            int r = (tid >> 5) + i * 8;
            int gr = row0 + r;
            At[r][tid & 31] = (gr < NN) ? Hl[(size_t)gr * 128 + kb + (tid & 31)] : 0.f;
        }
        __syncthreads();
#pragma unroll 4
        for (int k = 0; k < 32; ++k) {
            float4 wv = *(const float4*)&Wt[k][tx * 4];
#pragma unroll
            for (int j = 0; j < 4; ++j) {
                float a = At[ty * 4 + j][k];
                acc[j][0] += a * wv.x;
                acc[j][1] += a * wv.y;
                acc[j][2] += a * wv.z;
                acc[j][3] += a * wv.w;
            }
        }
        __syncthreads();
    }
#pragma unroll
    for (int j = 0; j < 4; ++j) {
        int r = row0 + ty * 4 + j;
        if (r < NN) {
            float4 prev;
            if (first) prev = *(const float4*)&linb[tx * 4];
            else       prev = *(const float4*)&logits[(size_t)r * 64 + tx * 4];
            float4 o = make_float4(prev.x + acc[j][0], prev.y + acc[j][1],
                                   prev.z + acc[j][2], prev.w + acc[j][3]);
            *(float4*)&logits[(size_t)r * 64 + tx * 4] = o;
        }
    }
}

// in-place log_softmax over rows of 64; one wave per row
__global__ __launch_bounds__(256) void k_lsm(float* __restrict__ logits) {
    int w = threadIdx.x >> 6, lane = threadIdx.x & 63;
    int r = blockIdx.x * 4 + w;
    if (r >= NN) return;
    float v = logits[(size_t)r * 64 + lane];
    float m = v;
#pragma unroll
    for (int off = 32; off; off >>= 1) m = fmaxf(m, __shfl_xor(m, off));
    float e = expf(v - m);
    float s = e;
#pragma unroll
    for (int off = 32; off; off >>= 1) s += __shfl_xor(s, off);
    logits[(size_t)r * 64 + lane] = v - m - logf(s);
}

// ---------------- launch ----------------

extern "C" void kernel_launch(void* const* d_in, const int* in_sizes, int n_in,
                              void* d_out, int out_size, void* d_ws, size_t ws_size,
                              hipStream_t stream) {
    const float* x    = (const float*)d_in[0];
    const int*   ei   = (const int*)d_in[1];
    const float* W[4] = {(const float*)d_in[2], (const float*)d_in[4],
                         (const float*)d_in[6], (const float*)d_in[8]};
    const float* b[4] = {(const float*)d_in[3], (const float*)d_in[5],
                         (const float*)d_in[7], (const float*)d_in[9]};
    const float* linW = (const float*)d_in[10];
    const float* linb = (const float*)d_in[11];
    float* out = (float*)d_out;     // logits accumulate here, log_softmax in place

    char* wp = (char*)d_ws;
    auto alloc = [&](size_t bytes) {
        void* p = (void*)wp;
        wp += (bytes + 255) & ~(size_t)255;
        return p;
    };
    int*   flag   = (int*)  alloc(4);
    int*   deg    = (int*)  alloc((size_t)NN * 4);
    float* dinv   = (float*)alloc((size_t)NN * 4);
    int*   rowptr = (int*)  alloc((size_t)(NN + 1) * 4);
    int*   cursor = (int*)  alloc((size_t)NN * 4);
    int*   bsum   = (int*)  alloc(512);
    int*   boff   = (int*)  alloc(512);
    int*   csr    = (int*)  alloc((size_t)NTOT * 4);
    float* bufA   = (float*)alloc((size_t)NN * HF * 4);
    float* bufB   = (float*)alloc((size_t)NN * HF * 4);
    float* bufC   = (float*)alloc((size_t)NN * HF * 4);

    dim3 blk(256);
    k_init  <<<391, blk, 0, stream>>>(flag, deg);
    k_detect<<<1024, blk, 0, stream>>>(ei, flag);
    k_hist  <<<6250, blk, 0, stream>>>(ei, flag, deg);
    k_dinv  <<<391, blk, 0, stream>>>(deg, dinv);
    k_scanA <<<98, blk, 0, stream>>>(deg, rowptr, bsum);
    k_scanB <<<1, dim3(128), 0, stream>>>(bsum, boff, rowptr);
    k_scanC <<<391, blk, 0, stream>>>(rowptr, boff, cursor);
    k_scatter<<<6641, blk, 0, stream>>>(ei, flag, cursor, csr);

    // layer rotation over 3 buffers: (in, m, out)
    const float* lin[4] = {x, bufB, bufC, bufB};
    float*       lout[4] = {bufB, bufC, bufB, bufC};
    for (int l = 0; l < 4; ++l) {
        k_mm128<<<1563, blk, 0, stream>>>(lin[l], W[l], dinv, bufA);
        k_agg  <<<25000, blk, 0, stream>>>(rowptr, csr, bufA, dinv, b[l], lout[l]);
        k_jk   <<<1563, blk, 0, stream>>>(lout[l], linW + (size_t)l * 128 * 64,
                                          linb, out, l == 0);
    }
    k_lsm<<<25000, blk, 0, stream>>>(out);
}

// Round 2
// 915.960 us; speedup vs baseline: 1.2100x; 1.2100x over previous
//
#include <hip/hip_runtime.h>
#include <cstdint>
#include <cstddef>

#define NN 100000
#define NE 1600000
#define NTOT (NE + NN)      // 1700000 edges incl self-loops
#define HF 128              // hidden features
#define OF 64               // output features

// ---------------- helpers ----------------

__device__ __forceinline__ unsigned int f2bf_rne(float f) {
    unsigned int u = __float_as_uint(f);
    return (u + 0x7fffu + ((u >> 16) & 1u)) >> 16;
}
__device__ __forceinline__ unsigned int pack_bf2(float lo, float hi) {
    return f2bf_rne(lo) | (f2bf_rne(hi) << 16);
}

// ---------------- graph preprocessing ----------------

__global__ __launch_bounds__(256) void k_init(int* flag, int* deg) {
    int i = blockIdx.x * 256 + threadIdx.x;
    if (i == 0) *flag = 0;
    if (i < NN) deg[i] = 1;   // self-loop
}

// OR-reduce odd 32-bit words of edge_index: all zero <=> data is int64.
__global__ __launch_bounds__(256) void k_detect(const int* ei, int* flag) {
    int t = blockIdx.x * blockDim.x + threadIdx.x;
    int v = 0;
    for (int i = t; i < NE; i += gridDim.x * blockDim.x) v |= ei[2 * i + 1];
    unsigned long long b = __ballot(v != 0);
    if ((threadIdx.x & 63) == 0 && b) atomicOr(flag, 1);
}

__device__ __forceinline__ int edge_src(const int* ei, int e, bool is64) {
    return is64 ? ei[2 * e] : ei[e];
}
__device__ __forceinline__ int edge_dst(const int* ei, int e, bool is64) {
    return is64 ? ei[2 * (NE + e)] : ei[NE + e];
}

__global__ __launch_bounds__(256) void k_hist(const int* ei, const int* flag, int* deg) {
    int e = blockIdx.x * 256 + threadIdx.x;
    if (e >= NE) return;
    bool is64 = (*flag) == 0;
    atomicAdd(&deg[edge_dst(ei, e, is64)], 1);
}

// exclusive scan of deg[N] -> rowptr (partial), also dinv = rsqrt(deg)
__global__ __launch_bounds__(256) void k_scanA(const int* deg, int* rowptr, int* bsum,
                                               float* dinv) {
    __shared__ int sh[256];
    int tid = threadIdx.x;
    int base = blockIdx.x * 1024 + tid * 4;
    int v0 = 0, v1 = 0, v2 = 0, v3 = 0;
    if (base + 0 < NN) v0 = deg[base + 0];
    if (base + 1 < NN) v1 = deg[base + 1];
    if (base + 2 < NN) v2 = deg[base + 2];
    if (base + 3 < NN) v3 = deg[base + 3];
    if (base + 0 < NN) dinv[base + 0] = rsqrtf((float)v0);
    if (base + 1 < NN) dinv[base + 1] = rsqrtf((float)v1);
    if (base + 2 < NN) dinv[base + 2] = rsqrtf((float)v2);
    if (base + 3 < NN) dinv[base + 3] = rsqrtf((float)v3);
    int s = v0 + v1 + v2 + v3;
    sh[tid] = s;
    __syncthreads();
    for (int off = 1; off < 256; off <<= 1) {
        int t = (tid >= off) ? sh[tid - off] : 0;
        __syncthreads();
        sh[tid] += t;
        __syncthreads();
    }
    int run = sh[tid] - s;
    if (base + 0 < NN) rowptr[base + 0] = run; run += v0;
    if (base + 1 < NN) rowptr[base + 1] = run; run += v1;
    if (base + 2 < NN) rowptr[base + 2] = run; run += v2;
    if (base + 3 < NN) rowptr[base + 3] = run;
    if (tid == 255) bsum[blockIdx.x] = sh[255];
}

__global__ __launch_bounds__(128) void k_scanB(const int* bsum, int* boff, int* rowptr) {
    __shared__ int sh[128];
    int tid = threadIdx.x;
    int v = (tid < 98) ? bsum[tid] : 0;
    sh[tid] = v;
    __syncthreads();
    for (int off = 1; off < 128; off <<= 1) {
        int t = (tid >= off) ? sh[tid - off] : 0;
        __syncthreads();
        sh[tid] += t;
        __syncthreads();
    }
    if (tid < 98) boff[tid] = sh[tid] - v;
    if (tid == 0) rowptr[NN] = NTOT;
}

__global__ __launch_bounds__(256) void k_scanC(int* rowptr, const int* boff, int* cursor) {
    int i = blockIdx.x * 256 + threadIdx.x;
    if (i < NN) {
        int r = rowptr[i] + boff[i >> 10];
        rowptr[i] = r;
        cursor[i] = r;
    }
}

__global__ __launch_bounds__(256) void k_scatter(const int* ei, const int* flag,
                                                 int* cursor, int* csr) {
    int e = blockIdx.x * 256 + threadIdx.x;
    if (e >= NTOT) return;
    bool is64 = (*flag) == 0;
    int s, d;
    if (e < NE) { s = edge_src(ei, e, is64); d = edge_dst(ei, e, is64); }
    else        { s = e - NE; d = s; }
    int pos = atomicAdd(&cursor[d], 1);
    csr[pos] = s;
}

// ---------------- dense compute ----------------

// Fused: m[r][:]      = bf16( dinv[r] * (A[r][:] @ W) )        [N][128] bf16
//        logits[r][:] (+)= A[r][:] @ Wjk  (+ linb if first)     [N][64]  f32 (if Wjk)
// block 256 thr, 64-row tile; tx=tid&31 -> 4 m-cols (2 jk-cols), ty=tid>>5 -> 8 rows
__global__ __launch_bounds__(256) void k_mmf(const float* __restrict__ A,
                                             const float* __restrict__ W,
                                             const float* __restrict__ dinv,
                                             const float* __restrict__ Wjk,
                                             const float* __restrict__ linb,
                                             float* __restrict__ logits, int first,
                                             unsigned int* __restrict__ m) {
    __shared__ float At[32][68];    // transposed: At[k][r]; 68 pad => b128-aligned reads
    __shared__ float Wt[32][128];
    __shared__ float Wjt[32][64];
    int tid = threadIdx.x;
    int tx = tid & 31, ty = tid >> 5;
    int row0 = blockIdx.x * 64;
    bool has_jk = (Wjk != nullptr);

    float acc[8][4];
    float accj[8][2];
#pragma unroll
    for (int j = 0; j < 8; ++j) {
#pragma unroll
        for (int c = 0; c < 4; ++c) acc[j][c] = 0.f;
        accj[j][0] = accj[j][1] = 0.f;
    }

    for (int kb = 0; kb < 128; kb += 32) {
#pragma unroll
        for (int i = 0; i < 4; ++i) {                 // W chunk 32x128
            int kr = ty + i * 8;
            float4 wv = *(const float4*)&W[(size_t)(kb + kr) * 128 + tx * 4];
            *(float4*)&Wt[kr][tx * 4] = wv;
        }
        if (has_jk) {
#pragma unroll
            for (int i = 0; i < 4; ++i) {             // Wjk chunk 32x64
                int kr = ty + i * 8;
                float2 wv = *(const float2*)&Wjk[(size_t)(kb + kr) * 64 + tx * 2];
                *(float2*)&Wjt[kr][tx * 2] = wv;
            }
        }
#pragma unroll
        for (int i = 0; i < 2; ++i) {                 // A chunk 64x32, transposed store
            int idx = tid + i * 256;
            int r = idx >> 3, c4 = idx & 7;
            int gr = row0 + r;
            float4 v = make_float4(0.f, 0.f, 0.f, 0.f);
            if (gr < NN) v = *(const float4*)&A[(size_t)gr * 128 + kb + c4 * 4];
            At[c4 * 4 + 0][r] = v.x;
            At[c4 * 4 + 1][r] = v.y;
            At[c4 * 4 + 2][r] = v.z;
            At[c4 * 4 + 3][r] = v.w;
        }
        __syncthreads();
#pragma unroll 4
        for (int k = 0; k < 32; ++k) {
            float4 a0 = *(const float4*)&At[k][ty * 8];
            float4 a1 = *(const float4*)&At[k][ty * 8 + 4];
            float4 wv = *(const float4*)&Wt[k][tx * 4];
            float a[8] = {a0.x, a0.y, a0.z, a0.w, a1.x, a1.y, a1.z, a1.w};
#pragma unroll
            for (int j = 0; j < 8; ++j) {
                acc[j][0] += a[j] * wv.x;
                acc[j][1] += a[j] * wv.y;
                acc[j][2] += a[j] * wv.z;
                acc[j][3] += a[j] * wv.w;
            }
            if (has_jk) {
                float2 wj = *(const float2*)&Wjt[k][tx * 2];
#pragma unroll
                for (int j = 0; j < 8; ++j) {
                    accj[j][0] += a[j] * wj.x;
                    accj[j][1] += a[j] * wj.y;
                }
            }
        }
        __syncthreads();
    }
#pragma unroll
    for (int j = 0; j < 8; ++j) {
        int r = row0 + ty * 8 + j;
        if (r < NN) {
            float sc = dinv[r];
            uint2 o;
            o.x = pack_bf2(acc[j][0] * sc, acc[j][1] * sc);
            o.y = pack_bf2(acc[j][2] * sc, acc[j][3] * sc);
            *(uint2*)&m[(size_t)r * 64 + tx * 2] = o;
            if (has_jk) {
                float2 prev;
                if (first) prev = *(const float2*)&linb[tx * 2];
                else       prev = *(const float2*)&logits[(size_t)r * 64 + tx * 2];
                float2 ov = make_float2(prev.x + accj[j][0], prev.y + accj[j][1]);
                *(float2*)&logits[(size_t)r * 64 + tx * 2] = ov;
            }
        }
    }
}

// h_out[d][:] = relu(dinv[d] * sum_{s in N(d)} bf16m[s][:] + b)   one wave per node
__global__ __launch_bounds__(256) void k_agg(const int* __restrict__ rowptr,
                                             const int* __restrict__ csr,
                                             const unsigned int* __restrict__ m,
                                             const float* __restrict__ dinv,
                                             const float* __restrict__ bias,
                                             float* __restrict__ out) {
    int w = threadIdx.x >> 6, lane = threadIdx.x & 63;
    int node = blockIdx.x * 4 + w;
    if (node >= NN) return;
    int beg = rowptr[node], end = rowptr[node + 1];
    float ax = 0.f, ay = 0.f;
    int i = beg;
    for (; i + 4 <= end; i += 4) {
        int s0 = csr[i], s1 = csr[i + 1], s2 = csr[i + 2], s3 = csr[i + 3];
        unsigned int u0 = m[(size_t)s0 * 64 + lane];
        unsigned int u1 = m[(size_t)s1 * 64 + lane];
        unsigned int u2 = m[(size_t)s2 * 64 + lane];
        unsigned int u3 = m[(size_t)s3 * 64 + lane];
        ax += __uint_as_float(u0 << 16) + __uint_as_float(u1 << 16)
            + __uint_as_float(u2 << 16) + __uint_as_float(u3 << 16);
        ay += __uint_as_float(u0 & 0xffff0000u) + __uint_as_float(u1 & 0xffff0000u)
            + __uint_as_float(u2 & 0xffff0000u) + __uint_as_float(u3 & 0xffff0000u);
    }
    for (; i < end; ++i) {
        unsigned int u = m[(size_t)csr[i] * 64 + lane];
        ax += __uint_as_float(u << 16);
        ay += __uint_as_float(u & 0xffff0000u);
    }
    float sc = dinv[node];
    float2 bb = ((const float2*)bias)[lane];
    float rx = fmaxf(ax * sc + bb.x, 0.f);
    float ry = fmaxf(ay * sc + bb.y, 0.f);
    ((float2*)out)[(size_t)node * 64 + lane] = make_float2(rx, ry);
}

// Final: logits[r][:] += H[r][:] @ Wl; then in-place log_softmax (width-16 shuffle).
// tx=tid&15 -> 4 cols, ty=tid>>4 -> 4 rows; the 16 lanes owning a row are contiguous.
__global__ __launch_bounds__(256) void k_jk_lsm(const float* __restrict__ Hl,
                                                const float* __restrict__ Wl,
                                                float* __restrict__ logits) {
    __shared__ float At[32][68];
    __shared__ float Wt[32][64];
    int tid = threadIdx.x;
    int tx = tid & 15, ty = tid >> 4;
    int row0 = blockIdx.x * 64;
    float acc[4][4];
#pragma unroll
    for (int j = 0; j < 4; ++j)
#pragma unroll
        for (int c = 0; c < 4; ++c) acc[j][c] = 0.f;

    for (int kb = 0; kb < 128; kb += 32) {
#pragma unroll
        for (int i = 0; i < 2; ++i) {                 // Wl chunk 32x64
            int kr = ty + i * 16;
            float4 wv = *(const float4*)&Wl[(size_t)(kb + kr) * 64 + tx * 4];
            *(float4*)&Wt[kr][tx * 4] = wv;
        }
#pragma unroll
        for (int i = 0; i < 2; ++i) {                 // A chunk 64x32, transposed
            int idx = tid + i * 256;
            int r = idx >> 3, c4 = idx & 7;
            int gr = row0 + r;
            float4 v = make_float4(0.f, 0.f, 0.f, 0.f);
            if (gr < NN) v = *(const float4*)&Hl[(size_t)gr * 128 + kb + c4 * 4];
            At[c4 * 4 + 0][r] = v.x;
            At[c4 * 4 + 1][r] = v.y;
            At[c4 * 4 + 2][r] = v.z;
            At[c4 * 4 + 3][r] = v.w;
        }
        __syncthreads();
#pragma unroll 4
        for (int k = 0; k < 32; ++k) {
            float4 a4 = *(const float4*)&At[k][ty * 4];
            float4 wv = *(const float4*)&Wt[k][tx * 4];
            float a[4] = {a4.x, a4.y, a4.z, a4.w};
#pragma unroll
            for (int j = 0; j < 4; ++j) {
                acc[j][0] += a[j] * wv.x;
                acc[j][1] += a[j] * wv.y;
                acc[j][2] += a[j] * wv.z;
                acc[j][3] += a[j] * wv.w;
            }
        }
        __syncthreads();
    }
#pragma unroll
    for (int j = 0; j < 4; ++j) {
        int r = row0 + ty * 4 + j;
        if (r < NN) {
            float4 prev = *(const float4*)&logits[(size_t)r * 64 + tx * 4];
            float v0 = prev.x + acc[j][0];
            float v1 = prev.y + acc[j][1];
            float v2 = prev.z + acc[j][2];
            float v3 = prev.w + acc[j][3];
            float mx = fmaxf(fmaxf(v0, v1), fmaxf(v2, v3));
#pragma unroll
            for (int s = 1; s < 16; s <<= 1) mx = fmaxf(mx, __shfl_xor(mx, s, 16));
            float e0 = expf(v0 - mx), e1 = expf(v1 - mx);
            float e2 = expf(v2 - mx), e3 = expf(v3 - mx);
            float sum = (e0 + e1) + (e2 + e3);
#pragma unroll
            for (int s = 1; s < 16; s <<= 1) sum += __shfl_xor(sum, s, 16);
            float ls = logf(sum) + mx;
            float4 o = make_float4(v0 - ls, v1 - ls, v2 - ls, v3 - ls);
            *(float4*)&logits[(size_t)r * 64 + tx * 4] = o;
        }
    }
}

// ---------------- launch ----------------

extern "C" void kernel_launch(void* const* d_in, const int* in_sizes, int n_in,
                              void* d_out, int out_size, void* d_ws, size_t ws_size,
                              hipStream_t stream) {
    const float* x    = (const float*)d_in[0];
    const int*   ei   = (const int*)d_in[1];
    const float* W[4] = {(const float*)d_in[2], (const float*)d_in[4],
                         (const float*)d_in[6], (const float*)d_in[8]};
    const float* b[4] = {(const float*)d_in[3], (const float*)d_in[5],
                         (const float*)d_in[7], (const float*)d_in[9]};
    const float* linW = (const float*)d_in[10];
    const float* linb = (const float*)d_in[11];
    float* out = (float*)d_out;

    char* wp = (char*)d_ws;
    auto alloc = [&](size_t bytes) {
        void* p = (void*)wp;
        wp += (bytes + 255) & ~(size_t)255;
        return p;
    };
    int*   flag   = (int*)  alloc(4);
    int*   deg    = (int*)  alloc((size_t)NN * 4);
    float* dinv   = (float*)alloc((size_t)NN * 4);
    int*   rowptr = (int*)  alloc((size_t)(NN + 1) * 4);
    int*   cursor = (int*)  alloc((size_t)NN * 4);
    int*   bsum   = (int*)  alloc(512);
    int*   boff   = (int*)  alloc(512);
    int*   csr    = (int*)  alloc((size_t)NTOT * 4);
    unsigned int* bufM = (unsigned int*)alloc((size_t)NN * 64 * 4);  // bf16 messages
    float* bufB   = (float*)alloc((size_t)NN * HF * 4);
    float* bufC   = (float*)alloc((size_t)NN * HF * 4);

    dim3 blk(256);
    k_init   <<<391, blk, 0, stream>>>(flag, deg);
    k_detect <<<1024, blk, 0, stream>>>(ei, flag);
    k_hist   <<<6250, blk, 0, stream>>>(ei, flag, deg);
    k_scanA  <<<98, blk, 0, stream>>>(deg, rowptr, bsum, dinv);
    k_scanB  <<<1, dim3(128), 0, stream>>>(bsum, boff, rowptr);
    k_scanC  <<<391, blk, 0, stream>>>(rowptr, boff, cursor);
    k_scatter<<<6641, blk, 0, stream>>>(ei, flag, cursor, csr);

    // layer l's matmul also accumulates layer (l-1)'s JK product (same A operand)
    const float* lin[4]  = {x, bufB, bufC, bufB};
    float*       lout[4] = {bufB, bufC, bufB, bufC};
    for (int l = 0; l < 4; ++l) {
        const float* wjk = (l == 0) ? nullptr : linW + (size_t)(l - 1) * 128 * 64;
        k_mmf<<<1563, blk, 0, stream>>>(lin[l], W[l], dinv, wjk, linb, out,
                                        l == 1 ? 1 : 0, bufM);
        k_agg<<<25000, blk, 0, stream>>>(rowptr, csr, bufM, dinv, b[l], lout[l]);
    }
    k_jk_lsm<<<1563, blk, 0, stream>>>(lout[3], linW + (size_t)3 * 128 * 64, out);
}

// Round 4
// 873.290 us; speedup vs baseline: 1.2691x; 1.0489x over previous
//
#include <hip/hip_runtime.h>
#include <cstdint>
#include <cstddef>

#define NN 100000
#define NE 1600000
#define NTOT (NE + NN)      // 1700000 edges incl self-loops
#define HF 128              // hidden features
#define OF 64               // output features

// ---------------- helpers ----------------

__device__ __forceinline__ unsigned int f2bf_rne(float f) {
    unsigned int u = __float_as_uint(f);
    return (u + 0x7fffu + ((u >> 16) & 1u)) >> 16;
}
__device__ __forceinline__ unsigned int pack_bf2(float lo, float hi) {
    return f2bf_rne(lo) | (f2bf_rne(hi) << 16);
}

// ---------------- graph preprocessing ----------------

__global__ __launch_bounds__(256) void k_init(int* flag, int* deg) {
    int i = blockIdx.x * 256 + threadIdx.x;
    if (i == 0) *flag = 0;
    if (i < NN) deg[i] = 1;   // self-loop
}

// OR-reduce odd 32-bit words of edge_index: all zero <=> data is int64.
__global__ __launch_bounds__(256) void k_detect(const int* ei, int* flag) {
    int t = blockIdx.x * blockDim.x + threadIdx.x;
    int v = 0;
    for (int i = t; i < NE; i += gridDim.x * blockDim.x) v |= ei[2 * i + 1];
    unsigned long long b = __ballot(v != 0);
    if ((threadIdx.x & 63) == 0 && b) atomicOr(flag, 1);
}

__device__ __forceinline__ int edge_src(const int* ei, int e, bool is64) {
    return is64 ? ei[2 * e] : ei[e];
}
__device__ __forceinline__ int edge_dst(const int* ei, int e, bool is64) {
    return is64 ? ei[2 * (NE + e)] : ei[NE + e];
}

__global__ __launch_bounds__(256) void k_hist(const int* ei, const int* flag, int* deg) {
    int e = blockIdx.x * 256 + threadIdx.x;
    if (e >= NE) return;
    bool is64 = (*flag) == 0;
    atomicAdd(&deg[edge_dst(ei, e, is64)], 1);
}

// exclusive scan of deg[N] -> rowptr (partial), also dinv = rsqrt(deg)
__global__ __launch_bounds__(256) void k_scanA(const int* deg, int* rowptr, int* bsum,
                                               float* dinv) {
    __shared__ int sh[256];
    int tid = threadIdx.x;
    int base = blockIdx.x * 1024 + tid * 4;
    int v0 = 0, v1 = 0, v2 = 0, v3 = 0;
    if (base + 0 < NN) v0 = deg[base + 0];
    if (base + 1 < NN) v1 = deg[base + 1];
    if (base + 2 < NN) v2 = deg[base + 2];
    if (base + 3 < NN) v3 = deg[base + 3];
    if (base + 0 < NN) dinv[base + 0] = rsqrtf((float)v0);
    if (base + 1 < NN) dinv[base + 1] = rsqrtf((float)v1);
    if (base + 2 < NN) dinv[base + 2] = rsqrtf((float)v2);
    if (base + 3 < NN) dinv[base + 3] = rsqrtf((float)v3);
    int s = v0 + v1 + v2 + v3;
    sh[tid] = s;
    __syncthreads();
    for (int off = 1; off < 256; off <<= 1) {
        int t = (tid >= off) ? sh[tid - off] : 0;
        __syncthreads();
        sh[tid] += t;
        __syncthreads();
    }
    int run = sh[tid] - s;
    if (base + 0 < NN) rowptr[base + 0] = run; run += v0;
    if (base + 1 < NN) rowptr[base + 1] = run; run += v1;
    if (base + 2 < NN) rowptr[base + 2] = run; run += v2;
    if (base + 3 < NN) rowptr[base + 3] = run;
    if (tid == 255) bsum[blockIdx.x] = sh[255];
}

__global__ __launch_bounds__(128) void k_scanB(const int* bsum, int* boff, int* rowptr) {
    __shared__ int sh[128];
    int tid = threadIdx.x;
    int v = (tid < 98) ? bsum[tid] : 0;
    sh[tid] = v;
    __syncthreads();
    for (int off = 1; off < 128; off <<= 1) {
        int t = (tid >= off) ? sh[tid - off] : 0;
        __syncthreads();
        sh[tid] += t;
        __syncthreads();
    }
    if (tid < 98) boff[tid] = sh[tid] - v;
    if (tid == 0) rowptr[NN] = NTOT;
}

__global__ __launch_bounds__(256) void k_scanC(int* rowptr, const int* boff, int* cursor) {
    int i = blockIdx.x * 256 + threadIdx.x;
    if (i < NN) {
        int r = rowptr[i] + boff[i >> 10];
        rowptr[i] = r;
        cursor[i] = r;
    }
}

__global__ __launch_bounds__(256) void k_scatter(const int* ei, const int* flag,
                                                 int* cursor, int* csr) {
    int e = blockIdx.x * 256 + threadIdx.x;
    if (e >= NTOT) return;
    bool is64 = (*flag) == 0;
    int s, d;
    if (e < NE) { s = edge_src(ei, e, is64); d = edge_dst(ei, e, is64); }
    else        { s = e - NE; d = s; }
    int pos = atomicAdd(&cursor[d], 1);
    csr[pos] = s;
}

// ---------------- dense compute ----------------

// Fused: m[r][:]      = bf16( dinv[r] * (A[r][:] @ W) )        [N][128] bf16
//        logits[r][:] (+)= A[r][:] @ Wjk  (+ linb if first)     [N][64]  f32 (if Wjk)
__global__ __launch_bounds__(256) void k_mmf(const float* __restrict__ A,
                                             const float* __restrict__ W,
                                             const float* __restrict__ dinv,
                                             const float* __restrict__ Wjk,
                                             const float* __restrict__ linb,
                                             float* __restrict__ logits, int first,
                                             unsigned int* __restrict__ m) {
    __shared__ float At[32][68];    // transposed: At[k][r]
    __shared__ float Wt[32][128];
    __shared__ float Wjt[32][64];
    int tid = threadIdx.x;
    int tx = tid & 31, ty = tid >> 5;
    int row0 = blockIdx.x * 64;
    bool has_jk = (Wjk != nullptr);

    float acc[8][4];
    float accj[8][2];
#pragma unroll
    for (int j = 0; j < 8; ++j) {
#pragma unroll
        for (int c = 0; c < 4; ++c) acc[j][c] = 0.f;
        accj[j][0] = accj[j][1] = 0.f;
    }

    for (int kb = 0; kb < 128; kb += 32) {
#pragma unroll
        for (int i = 0; i < 4; ++i) {                 // W chunk 32x128
            int kr = ty + i * 8;
            float4 wv = *(const float4*)&W[(size_t)(kb + kr) * 128 + tx * 4];
            *(float4*)&Wt[kr][tx * 4] = wv;
        }
        if (has_jk) {
#pragma unroll
            for (int i = 0; i < 4; ++i) {             // Wjk chunk 32x64
                int kr = ty + i * 8;
                float2 wv = *(const float2*)&Wjk[(size_t)(kb + kr) * 64 + tx * 2];
                *(float2*)&Wjt[kr][tx * 2] = wv;
            }
        }
#pragma unroll
        for (int i = 0; i < 2; ++i) {                 // A chunk 64x32, transposed store
            int idx = tid + i * 256;
            int r = idx >> 3, c4 = idx & 7;
            int gr = row0 + r;
            float4 v = make_float4(0.f, 0.f, 0.f, 0.f);
            if (gr < NN) v = *(const float4*)&A[(size_t)gr * 128 + kb + c4 * 4];
            At[c4 * 4 + 0][r] = v.x;
            At[c4 * 4 + 1][r] = v.y;
            At[c4 * 4 + 2][r] = v.z;
            At[c4 * 4 + 3][r] = v.w;
        }
        __syncthreads();
#pragma unroll 4
        for (int k = 0; k < 32; ++k) {
            float4 a0 = *(const float4*)&At[k][ty * 8];
            float4 a1 = *(const float4*)&At[k][ty * 8 + 4];
            float4 wv = *(const float4*)&Wt[k][tx * 4];
            float a[8] = {a0.x, a0.y, a0.z, a0.w, a1.x, a1.y, a1.z, a1.w};
#pragma unroll
            for (int j = 0; j < 8; ++j) {
                acc[j][0] += a[j] * wv.x;
                acc[j][1] += a[j] * wv.y;
                acc[j][2] += a[j] * wv.z;
                acc[j][3] += a[j] * wv.w;
            }
            if (has_jk) {
                float2 wj = *(const float2*)&Wjt[k][tx * 2];
#pragma unroll
                for (int j = 0; j < 8; ++j) {
                    accj[j][0] += a[j] * wj.x;
                    accj[j][1] += a[j] * wj.y;
                }
            }
        }
        __syncthreads();
    }
#pragma unroll
    for (int j = 0; j < 8; ++j) {
        int r = row0 + ty * 8 + j;
        if (r < NN) {
            float sc = dinv[r];
            uint2 o;
            o.x = pack_bf2(acc[j][0] * sc, acc[j][1] * sc);
            o.y = pack_bf2(acc[j][2] * sc, acc[j][3] * sc);
            *(uint2*)&m[(size_t)r * 64 + tx * 2] = o;
            if (has_jk) {
                float2 prev;
                if (first) prev = *(const float2*)&linb[tx * 2];
                else       prev = *(const float2*)&logits[(size_t)r * 64 + tx * 2];
                float2 ov = make_float2(prev.x + accj[j][0], prev.y + accj[j][1]);
                *(float2*)&logits[(size_t)r * 64 + tx * 2] = ov;
            }
        }
    }
}

// h_out[d][:] = relu(dinv[d] * sum_{s in N(d)} bf16m[s][:] + b)
// one wave per node; 4 groups of 16 lanes; group g gathers a full 256 B row
// (16 B/lane). All __shfl ops are executed by ALL 64 lanes (wave-uniform
// context) — a bpermute from an exec-masked-off lane is undefined, so the
// shuffle is hoisted out of the predicated tail accumulate.
__global__ __launch_bounds__(256) void k_agg(const int* __restrict__ rowptr,
                                             const int* __restrict__ csr,
                                             const uint4* __restrict__ m4,
                                             const float* __restrict__ dinv,
                                             const float* __restrict__ bias,
                                             float* __restrict__ out) {
    int w = threadIdx.x >> 6, lane = threadIdx.x & 63;
    int grp = lane >> 4, lj = lane & 15;
    int node = blockIdx.x * 4 + w;
    if (node >= NN) return;
    int beg = rowptr[node], end = rowptr[node + 1];

    float a[8];
#pragma unroll
    for (int q = 0; q < 8; ++q) a[q] = 0.f;

    for (int base = beg; base < end; base += 64) {
        int cnt = min(64, end - base);
        int sv = (lane < cnt) ? csr[base + lane] : 0;
        int k = 0;
        for (; k + 8 <= cnt; k += 8) {
            int sA = __shfl(sv, k + grp);
            int sB = __shfl(sv, k + 4 + grp);
            uint4 vA = m4[(size_t)sA * 16 + lj];
            uint4 vB = m4[(size_t)sB * 16 + lj];
            a[0] += __uint_as_float(vA.x << 16);
            a[1] += __uint_as_float(vA.x & 0xffff0000u);
            a[2] += __uint_as_float(vA.y << 16);
            a[3] += __uint_as_float(vA.y & 0xffff0000u);
            a[4] += __uint_as_float(vA.z << 16);
            a[5] += __uint_as_float(vA.z & 0xffff0000u);
            a[6] += __uint_as_float(vA.w << 16);
            a[7] += __uint_as_float(vA.w & 0xffff0000u);
            a[0] += __uint_as_float(vB.x << 16);
            a[1] += __uint_as_float(vB.x & 0xffff0000u);
            a[2] += __uint_as_float(vB.y << 16);
            a[3] += __uint_as_float(vB.y & 0xffff0000u);
            a[4] += __uint_as_float(vB.z << 16);
            a[5] += __uint_as_float(vB.z & 0xffff0000u);
            a[6] += __uint_as_float(vB.w << 16);
            a[7] += __uint_as_float(vB.w & 0xffff0000u);
        }
        if (k + 4 <= cnt) {       // wave-uniform condition; all lanes shuffle
            int s = __shfl(sv, k + grp);
            uint4 v = m4[(size_t)s * 16 + lj];
            a[0] += __uint_as_float(v.x << 16);
            a[1] += __uint_as_float(v.x & 0xffff0000u);
            a[2] += __uint_as_float(v.y << 16);
            a[3] += __uint_as_float(v.y & 0xffff0000u);
            a[4] += __uint_as_float(v.z << 16);
            a[5] += __uint_as_float(v.z & 0xffff0000u);
            a[6] += __uint_as_float(v.w << 16);
            a[7] += __uint_as_float(v.w & 0xffff0000u);
            k += 4;
        }
        int rem = cnt - k;              // 0..3
        if (rem) {                      // wave-uniform
            int idx = k + grp;          // clamp so the shfl index is in range;
            if (idx >= cnt) idx = cnt - 1;   // executed by ALL lanes (defined)
            int s = __shfl(sv, idx);
            if (grp < rem) {            // only the accumulate is predicated
                uint4 v = m4[(size_t)s * 16 + lj];
                a[0] += __uint_as_float(v.x << 16);
                a[1] += __uint_as_float(v.x & 0xffff0000u);
                a[2] += __uint_as_float(v.y << 16);
                a[3] += __uint_as_float(v.y & 0xffff0000u);
                a[4] += __uint_as_float(v.z << 16);
                a[5] += __uint_as_float(v.z & 0xffff0000u);
                a[6] += __uint_as_float(v.w << 16);
                a[7] += __uint_as_float(v.w & 0xffff0000u);
            }
        }
    }
    // combine the 4 groups (same features live in lanes lj, lj+16, lj+32, lj+48)
#pragma unroll
    for (int q = 0; q < 8; ++q) a[q] += __shfl_xor(a[q], 16);
#pragma unroll
    for (int q = 0; q < 8; ++q) a[q] += __shfl_xor(a[q], 32);

    float sc = dinv[node];
    if (grp == 0) {
        float4 bb = ((const float4*)bias)[lj * 2];
        float4 o = make_float4(fmaxf(a[0] * sc + bb.x, 0.f),
                               fmaxf(a[1] * sc + bb.y, 0.f),
                               fmaxf(a[2] * sc + bb.z, 0.f),
                               fmaxf(a[3] * sc + bb.w, 0.f));
        *(float4*)&out[(size_t)node * 128 + lj * 8] = o;
    } else if (grp == 1) {
        float4 bb = ((const float4*)bias)[lj * 2 + 1];
        float4 o = make_float4(fmaxf(a[4] * sc + bb.x, 0.f),
                               fmaxf(a[5] * sc + bb.y, 0.f),
                               fmaxf(a[6] * sc + bb.z, 0.f),
                               fmaxf(a[7] * sc + bb.w, 0.f));
        *(float4*)&out[(size_t)node * 128 + lj * 8 + 4] = o;
    }
}

// Final: logits[r][:] += H[r][:] @ Wl; then in-place log_softmax.
// The width-16 shuffle groups each own a single row r, so the `r < NN`
// predicate is uniform across every shuffle group (safe).
__global__ __launch_bounds__(256) void k_jk_lsm(const float* __restrict__ Hl,
                                                const float* __restrict__ Wl,
                                                float* __restrict__ logits) {
    __shared__ float At[32][68];
    __shared__ float Wt[32][64];
    int tid = threadIdx.x;
    int tx = tid & 15, ty = tid >> 4;
    int row0 = blockIdx.x * 64;
    float acc[4][4];
#pragma unroll
    for (int j = 0; j < 4; ++j)
#pragma unroll
        for (int c = 0; c < 4; ++c) acc[j][c] = 0.f;

    for (int kb = 0; kb < 128; kb += 32) {
#pragma unroll
        for (int i = 0; i < 2; ++i) {                 // Wl chunk 32x64
            int kr = ty + i * 16;
            float4 wv = *(const float4*)&Wl[(size_t)(kb + kr) * 64 + tx * 4];
            *(float4*)&Wt[kr][tx * 4] = wv;
        }
#pragma unroll
        for (int i = 0; i < 2; ++i) {                 // A chunk 64x32, transposed
            int idx = tid + i * 256;
            int r = idx >> 3, c4 = idx & 7;
            int gr = row0 + r;
            float4 v = make_float4(0.f, 0.f, 0.f, 0.f);
            if (gr < NN) v = *(const float4*)&Hl[(size_t)gr * 128 + kb + c4 * 4];
            At[c4 * 4 + 0][r] = v.x;
            At[c4 * 4 + 1][r] = v.y;
            At[c4 * 4 + 2][r] = v.z;
            At[c4 * 4 + 3][r] = v.w;
        }
        __syncthreads();
#pragma unroll 4
        for (int k = 0; k < 32; ++k) {
            float4 a4 = *(const float4*)&At[k][ty * 4];
            float4 wv = *(const float4*)&Wt[k][tx * 4];
            float a[4] = {a4.x, a4.y, a4.z, a4.w};
#pragma unroll
            for (int j = 0; j < 4; ++j) {
                acc[j][0] += a[j] * wv.x;
                acc[j][1] += a[j] * wv.y;
                acc[j][2] += a[j] * wv.z;
                acc[j][3] += a[j] * wv.w;
            }
        }
        __syncthreads();
    }
#pragma unroll
    for (int j = 0; j < 4; ++j) {
        int r = row0 + ty * 4 + j;
        if (r < NN) {
            float4 prev = *(const float4*)&logits[(size_t)r * 64 + tx * 4];
            float v0 = prev.x + acc[j][0];
            float v1 = prev.y + acc[j][1];
            float v2 = prev.z + acc[j][2];
            float v3 = prev.w + acc[j][3];
            float mx = fmaxf(fmaxf(v0, v1), fmaxf(v2, v3));
#pragma unroll
            for (int s = 1; s < 16; s <<= 1) mx = fmaxf(mx, __shfl_xor(mx, s, 16));
            float e0 = expf(v0 - mx), e1 = expf(v1 - mx);
            float e2 = expf(v2 - mx), e3 = expf(v3 - mx);
            float sum = (e0 + e1) + (e2 + e3);
#pragma unroll
            for (int s = 1; s < 16; s <<= 1) sum += __shfl_xor(sum, s, 16);
            float ls = logf(sum) + mx;
            float4 o = make_float4(v0 - ls, v1 - ls, v2 - ls, v3 - ls);
            *(float4*)&logits[(size_t)r * 64 + tx * 4] = o;
        }
    }
}

// ---------------- launch ----------------

extern "C" void kernel_launch(void* const* d_in, const int* in_sizes, int n_in,
                              void* d_out, int out_size, void* d_ws, size_t ws_size,
                              hipStream_t stream) {
    const float* x    = (const float*)d_in[0];
    const int*   ei   = (const int*)d_in[1];
    const float* W[4] = {(const float*)d_in[2], (const float*)d_in[4],
                         (const float*)d_in[6], (const float*)d_in[8]};
    const float* b[4] = {(const float*)d_in[3], (const float*)d_in[5],
                         (const float*)d_in[7], (const float*)d_in[9]};
    const float* linW = (const float*)d_in[10];
    const float* linb = (const float*)d_in[11];
    float* out = (float*)d_out;

    char* wp = (char*)d_ws;
    auto alloc = [&](size_t bytes) {
        void* p = (void*)wp;
        wp += (bytes + 255) & ~(size_t)255;
        return p;
    };
    int*   flag   = (int*)  alloc(4);
    int*   deg    = (int*)  alloc((size_t)NN * 4);
    float* dinv   = (float*)alloc((size_t)NN * 4);
    int*   rowptr = (int*)  alloc((size_t)(NN + 1) * 4);
    int*   cursor = (int*)  alloc((size_t)NN * 4);
    int*   bsum   = (int*)  alloc(512);
    int*   boff   = (int*)  alloc(512);
    int*   csr    = (int*)  alloc((size_t)NTOT * 4);
    unsigned int* bufM = (unsigned int*)alloc((size_t)NN * 64 * 4);  // bf16 messages
    float* bufB   = (float*)alloc((size_t)NN * HF * 4);
    float* bufC   = (float*)alloc((size_t)NN * HF * 4);

    dim3 blk(256);
    k_init   <<<391, blk, 0, stream>>>(flag, deg);
    k_detect <<<1024, blk, 0, stream>>>(ei, flag);
    k_hist   <<<6250, blk, 0, stream>>>(ei, flag, deg);
    k_scanA  <<<98, blk, 0, stream>>>(deg, rowptr, bsum, dinv);
    k_scanB  <<<1, dim3(128), 0, stream>>>(bsum, boff, rowptr);
    k_scanC  <<<391, blk, 0, stream>>>(rowptr, boff, cursor);
    k_scatter<<<6641, blk, 0, stream>>>(ei, flag, cursor, csr);

    const float* lin[4]  = {x, bufB, bufC, bufB};
    float*       lout[4] = {bufB, bufC, bufB, bufC};
    for (int l = 0; l < 4; ++l) {
        const float* wjk = (l == 0) ? nullptr : linW + (size_t)(l - 1) * 128 * 64;
        k_mmf<<<1563, blk, 0, stream>>>(lin[l], W[l], dinv, wjk, linb, out,
                                        l == 1 ? 1 : 0, bufM);
        k_agg<<<25000, blk, 0, stream>>>(rowptr, csr, (const uint4*)bufM, dinv,
                                         b[l], lout[l]);
    }
    k_jk_lsm<<<1563, blk, 0, stream>>>(lout[3], linW + (size_t)3 * 128 * 64, out);
}